// Round 1
// baseline (48.870 us; speedup 1.0000x reference)
//
#include <hip/hip_runtime.h>

// WaveletSparsityPrior: 3-level Haar pyramid sparsity loss on (64,1,1024,1024) f32.
// One thread owns an 8x8 tile -> full 3-level pyramid in registers.
// Stage 1: 4096 blocks x 256 threads, per-block partial sums -> d_ws.
// Stage 2: single block deterministic reduction -> d_out[0].

#define NBLK 4096

static __device__ __forceinline__ float band3(float lh, float hl, float hh, float thr) {
    return fminf(fabsf(lh), thr) + fminf(fabsf(hl), thr) + fminf(fabsf(hh), thr);
}

__global__ __launch_bounds__(256) void wsp_partial(const float* __restrict__ pred,
                                                   float* __restrict__ partial) {
    const int tid = blockIdx.x * 256 + threadIdx.x;   // tile index, 0..1048575
    const int tx = tid & 127;          // tile col (8 cols each)
    const int ty = (tid >> 7) & 127;   // tile row (8 rows each)
    const int b  = tid >> 14;          // batch

    // base of this thread's 8x8 tile: b*1024*1024 + ty*8*1024 + tx*8
    const float* base = pred + ((size_t)b << 20) + ((size_t)ty << 13) + ((size_t)tx << 3);

    const float T1 = (50.0f / 255.0f) * 0.25f;  // level_idx=3
    const float T2 = (50.0f / 255.0f) * 0.5f;   // level_idx=2
    const float T3 = (50.0f / 255.0f);          // level_idx=1

    float ll1[4][4];
    float s1 = 0.0f, s2 = 0.0f, s3 = 0.0f;

    // ---- level 1: 8x8 -> 4x4 per band (factor INV_SQRT2^2 = 0.5 folded in) ----
    #pragma unroll
    for (int r = 0; r < 4; ++r) {
        const float* r0 = base + ((size_t)(2 * r) << 10);
        const float* r1 = r0 + 1024;
        float4 a0 = *reinterpret_cast<const float4*>(r0);
        float4 a1 = *reinterpret_cast<const float4*>(r0 + 4);
        float4 b0 = *reinterpret_cast<const float4*>(r1);
        float4 b1 = *reinterpret_cast<const float4*>(r1 + 4);
        float lo[8], hi[8];
        lo[0] = a0.x + b0.x; hi[0] = b0.x - a0.x;
        lo[1] = a0.y + b0.y; hi[1] = b0.y - a0.y;
        lo[2] = a0.z + b0.z; hi[2] = b0.z - a0.z;
        lo[3] = a0.w + b0.w; hi[3] = b0.w - a0.w;
        lo[4] = a1.x + b1.x; hi[4] = b1.x - a1.x;
        lo[5] = a1.y + b1.y; hi[5] = b1.y - a1.y;
        lo[6] = a1.z + b1.z; hi[6] = b1.z - a1.z;
        lo[7] = a1.w + b1.w; hi[7] = b1.w - a1.w;
        #pragma unroll
        for (int c = 0; c < 4; ++c) {
            float ll = (lo[2 * c] + lo[2 * c + 1]) * 0.5f;
            float lh = (lo[2 * c + 1] - lo[2 * c]) * 0.5f;
            float hl = (hi[2 * c] + hi[2 * c + 1]) * 0.5f;
            float hh = (hi[2 * c + 1] - hi[2 * c]) * 0.5f;
            s1 += band3(lh, hl, hh, T1);
            ll1[r][c] = ll;
        }
    }

    // ---- level 2: 4x4 -> 2x2 per band ----
    float ll2[2][2];
    #pragma unroll
    for (int r = 0; r < 2; ++r) {
        float lo[4], hi[4];
        #pragma unroll
        for (int c = 0; c < 4; ++c) {
            lo[c] = ll1[2 * r][c] + ll1[2 * r + 1][c];
            hi[c] = ll1[2 * r + 1][c] - ll1[2 * r][c];
        }
        #pragma unroll
        for (int c = 0; c < 2; ++c) {
            float ll = (lo[2 * c] + lo[2 * c + 1]) * 0.5f;
            float lh = (lo[2 * c + 1] - lo[2 * c]) * 0.5f;
            float hl = (hi[2 * c] + hi[2 * c + 1]) * 0.5f;
            float hh = (hi[2 * c + 1] - hi[2 * c]) * 0.5f;
            s2 += band3(lh, hl, hh, T2);
            ll2[r][c] = ll;
        }
    }

    // ---- level 3: 2x2 -> 1x1 per band ----
    {
        float lo0 = ll2[0][0] + ll2[1][0];
        float lo1 = ll2[0][1] + ll2[1][1];
        float hi0 = ll2[1][0] - ll2[0][0];
        float hi1 = ll2[1][1] - ll2[0][1];
        float lh = (lo1 - lo0) * 0.5f;
        float hl = (hi0 + hi1) * 0.5f;
        float hh = (hi1 - hi0) * 0.5f;
        s3 = band3(lh, hl, hh, T3);
    }

    // weights/(3*N_band): 1/(9*16777216), 1/(6*4194304), 1/(3*1048576)
    const float A1 = 1.0f / 150994944.0f;
    const float A2 = 1.0f / 25165824.0f;
    const float A3 = 1.0f / 3145728.0f;
    float c = s1 * A1 + s2 * A2 + s3 * A3;

    __shared__ float red[256];
    red[threadIdx.x] = c;
    __syncthreads();
    #pragma unroll
    for (int off = 128; off > 0; off >>= 1) {
        if (threadIdx.x < off) red[threadIdx.x] += red[threadIdx.x + off];
        __syncthreads();
    }
    if (threadIdx.x == 0) partial[blockIdx.x] = red[0];
}

__global__ __launch_bounds__(256) void wsp_reduce(const float* __restrict__ partial,
                                                  float* __restrict__ out) {
    __shared__ float red[256];
    float s = 0.0f;
    for (int i = threadIdx.x; i < NBLK; i += 256) s += partial[i];
    red[threadIdx.x] = s;
    __syncthreads();
    #pragma unroll
    for (int off = 128; off > 0; off >>= 1) {
        if (threadIdx.x < off) red[threadIdx.x] += red[threadIdx.x + off];
        __syncthreads();
    }
    if (threadIdx.x == 0) out[0] = red[0];
}

extern "C" void kernel_launch(void* const* d_in, const int* in_sizes, int n_in,
                              void* d_out, int out_size, void* d_ws, size_t ws_size,
                              hipStream_t stream) {
    const float* pred = (const float*)d_in[0];
    float* partial = (float*)d_ws;           // needs NBLK*4 = 16 KB
    float* out = (float*)d_out;

    wsp_partial<<<NBLK, 256, 0, stream>>>(pred, partial);
    wsp_reduce<<<1, 256, 0, stream>>>(partial, out);
}